// Round 1
// baseline (1103.408 us; speedup 1.0000x reference)
//
#include <hip/hip_runtime.h>
#include <math.h>

#define BB 2
#define TT 2048
#define DD 1024
#define NH 16
#define HDD 64

// ============================================================================
// Kernel 1: fused QKV projection.  C[m,e] = dot(x[m,:], W[e,:])  (NT GEMM)
// Tile 64x64, BK=16, 256 threads, 4x4 accumulators / thread.
// LDS tiles stored K-major (Xs[kk][row]) so the inner loop is 2x ds_read_b128
// + 16 v_fma per kk.  Pad 68 keeps float4 alignment and <=2-way bank aliasing.
// Output scattered to (B,H,T,HD) layout: per block, h is constant (n0>>6).
// ============================================================================
__global__ __launch_bounds__(256) void qkv_kernel(
    const float* __restrict__ x,
    const float* __restrict__ Wq, const float* __restrict__ Wk,
    const float* __restrict__ Wv,
    float* __restrict__ qo, float* __restrict__ ko, float* __restrict__ vo)
{
    __shared__ float Xs[16][68];
    __shared__ float Ws[16][68];

    const int tid = threadIdx.x;
    const int tx = tid & 15, ty = tid >> 4;
    const int lr = tid >> 2;            // 0..63 tile row for loads
    const int lc = (tid & 3) << 2;      // 0,4,8,12 k-offset for loads

    const int m0 = blockIdx.x * 64;
    const int nb = blockIdx.y;          // 0..47
    const int which = nb >> 4;          // 0=q 1=k 2=v
    const int n0 = (nb & 15) * 64;      // col within 1024
    const float* W = (which == 0) ? Wq : (which == 1) ? Wk : Wv;
    float* outp = (which == 0) ? qo : (which == 1) ? ko : vo;

    const float* xrow = x + (size_t)(m0 + lr) * DD + lc;
    const float* wrow = W + (size_t)(n0 + lr) * DD + lc;

    float acc[4][4] = {};

    for (int k0 = 0; k0 < DD; k0 += 16) {
        const float4 xa = *(const float4*)(xrow + k0);
        const float4 wa = *(const float4*)(wrow + k0);
        __syncthreads();
        Xs[lc + 0][lr] = xa.x; Xs[lc + 1][lr] = xa.y;
        Xs[lc + 2][lr] = xa.z; Xs[lc + 3][lr] = xa.w;
        Ws[lc + 0][lr] = wa.x; Ws[lc + 1][lr] = wa.y;
        Ws[lc + 2][lr] = wa.z; Ws[lc + 3][lr] = wa.w;
        __syncthreads();
#pragma unroll
        for (int kk = 0; kk < 16; ++kk) {
            const float4 a = *(const float4*)&Xs[kk][ty << 2];
            const float4 b = *(const float4*)&Ws[kk][tx << 2];
            const float av[4] = {a.x, a.y, a.z, a.w};
            const float bv[4] = {b.x, b.y, b.z, b.w};
#pragma unroll
            for (int i = 0; i < 4; ++i)
#pragma unroll
                for (int j = 0; j < 4; ++j)
                    acc[i][j] += av[i] * bv[j];
        }
    }

    // scatter to (B,H,T,HD); h constant per block, hd = tx*4+j contiguous
    const int h = n0 >> 6;
#pragma unroll
    for (int i = 0; i < 4; ++i) {
        const int m = m0 + (ty << 2) + i;
        const int b = m >> 11;          // /2048
        const int t = m & 2047;
        float4 st;
        st.x = acc[i][0]; st.y = acc[i][1]; st.z = acc[i][2]; st.w = acc[i][3];
        *(float4*)&outp[(((size_t)(b * NH + h) * TT + t) << 6) + (tx << 2)] = st;
    }
}

// ============================================================================
// Kernel 2: flash-style causal attention per (b,h).  One block per 64 q-rows.
// Q/K tiles stored d-major (Qs[d][i]); S stored transposed St[k][q] so the
// P*V inner loop reads ds_read_b128 on both operands.  Online softmax state
// (m,l,alpha) per q-row in LDS.  Mask: val=-inf where k>q on diagonal tile;
// matches ref (mask-then-scale == scale-then-mask for -inf).
// ============================================================================
__global__ __launch_bounds__(256) void attn_kernel(
    const float* __restrict__ q, const float* __restrict__ k,
    const float* __restrict__ v, float* __restrict__ ctx)
{
    __shared__ float Qs[HDD][68];
    __shared__ float Ks[HDD][68];
    __shared__ float Vs[64][HDD];
    __shared__ float St[64][68];
    __shared__ float mrow[64], lrow[64], arow[64];

    const int tid = threadIdx.x;
    const int tx = tid & 15, ty = tid >> 4;
    const int lr = tid >> 2;            // 0..63 row for loads
    const int lc = (tid & 3) << 4;      // 0,16,32,48 col base for loads

    const int qt = blockIdx.x;
    const int q0 = qt << 6;
    const int bh = blockIdx.y;
    const float* qb = q + (size_t)bh * TT * HDD;
    const float* kb = k + (size_t)bh * TT * HDD;
    const float* vb = v + (size_t)bh * TT * HDD;

    // load Q tile transposed: Qs[d][i]
#pragma unroll
    for (int u = 0; u < 4; ++u) {
        const float4 t4 = *(const float4*)&qb[(size_t)(q0 + lr) * HDD + lc + u * 4];
        Qs[lc + u * 4 + 0][lr] = t4.x;
        Qs[lc + u * 4 + 1][lr] = t4.y;
        Qs[lc + u * 4 + 2][lr] = t4.z;
        Qs[lc + u * 4 + 3][lr] = t4.w;
    }
    if (tid < 64) { mrow[tid] = -INFINITY; lrow[tid] = 0.f; }

    float o[4][4] = {};
    const float scale = 0.125f;         // 1/sqrt(64)

    for (int jt = 0; jt <= qt; ++jt) {
        const int k0 = jt << 6;
        __syncthreads();                // prev-iter St/Vs reads done
#pragma unroll
        for (int u = 0; u < 4; ++u) {
            const float4 t4 = *(const float4*)&kb[(size_t)(k0 + lr) * HDD + lc + u * 4];
            Ks[lc + u * 4 + 0][lr] = t4.x;
            Ks[lc + u * 4 + 1][lr] = t4.y;
            Ks[lc + u * 4 + 2][lr] = t4.z;
            Ks[lc + u * 4 + 3][lr] = t4.w;
            *(float4*)&Vs[lr][lc + u * 4] =
                *(const float4*)&vb[(size_t)(k0 + lr) * HDD + lc + u * 4];
        }
        __syncthreads();

        // S = Q * K^T  (4x4 per thread)
        float s[4][4] = {};
        for (int d = 0; d < HDD; ++d) {
            const float4 a = *(const float4*)&Qs[d][ty << 2];
            const float4 b = *(const float4*)&Ks[d][tx << 2];
            const float av[4] = {a.x, a.y, a.z, a.w};
            const float bv[4] = {b.x, b.y, b.z, b.w};
#pragma unroll
            for (int i = 0; i < 4; ++i)
#pragma unroll
                for (int j = 0; j < 4; ++j)
                    s[i][j] += av[i] * bv[j];
        }

        // scale + causal mask, write transposed St[k][q]
        const bool diag = (jt == qt);
#pragma unroll
        for (int i = 0; i < 4; ++i) {
            const int qi = q0 + (ty << 2) + i;
#pragma unroll
            for (int j = 0; j < 4; ++j) {
                const int kj = k0 + (tx << 2) + j;
                float val = s[i][j] * scale;
                if (diag && kj > qi) val = -INFINITY;
                St[(tx << 2) + j][(ty << 2) + i] = val;
            }
        }
        __syncthreads();

        // online softmax: 4 threads per q-row, 16 k each
        {
            const int r = tid >> 2, p = tid & 3;
            float mx = -INFINITY;
#pragma unroll
            for (int u = 0; u < 16; ++u) mx = fmaxf(mx, St[p * 16 + u][r]);
            mx = fmaxf(mx, __shfl_xor(mx, 1));
            mx = fmaxf(mx, __shfl_xor(mx, 2));
            const float m_old = mrow[r];
            const float m_new = fmaxf(m_old, mx);
            float sum = 0.f;
#pragma unroll
            for (int u = 0; u < 16; ++u) {
                const float pv = __expf(St[p * 16 + u][r] - m_new);
                St[p * 16 + u][r] = pv;
                sum += pv;
            }
            sum += __shfl_xor(sum, 1);
            sum += __shfl_xor(sum, 2);
            if (p == 0) {
                const float alpha = __expf(m_old - m_new);  // 0 on first tile
                mrow[r] = m_new;
                lrow[r] = lrow[r] * alpha + sum;
                arow[r] = alpha;
            }
        }
        __syncthreads();

        // O = O*alpha + P*V
        float al[4];
#pragma unroll
        for (int i = 0; i < 4; ++i) al[i] = arow[(ty << 2) + i];
#pragma unroll
        for (int i = 0; i < 4; ++i)
#pragma unroll
            for (int j = 0; j < 4; ++j) o[i][j] *= al[i];

        for (int kk = 0; kk < 64; ++kk) {
            const float4 a = *(const float4*)&St[kk][ty << 2];
            const float4 b = *(const float4*)&Vs[kk][tx << 2];
            const float av[4] = {a.x, a.y, a.z, a.w};
            const float bv[4] = {b.x, b.y, b.z, b.w};
#pragma unroll
            for (int i = 0; i < 4; ++i)
#pragma unroll
                for (int j = 0; j < 4; ++j)
                    o[i][j] += av[i] * bv[j];
        }
    }

    // normalize and store ctx in (B,H,T,HD) layout == faithful-reshape layout
    float* cb = ctx + (size_t)bh * TT * HDD;
#pragma unroll
    for (int i = 0; i < 4; ++i) {
        const float linv = 1.f / lrow[(ty << 2) + i];
        float4 st;
        st.x = o[i][0] * linv; st.y = o[i][1] * linv;
        st.z = o[i][2] * linv; st.w = o[i][3] * linv;
        *(float4*)&cb[(size_t)(q0 + (ty << 2) + i) * HDD + (tx << 2)] = st;
    }
}

// ============================================================================
// Kernel 3: output projection.  ctx buffer (B,H,T,HD)-contiguous read as
// (B*T, 1024) row-major — this IS the reference's no-transpose reshape.
// out[m,n] = dot(ctx[m,:], Wo[n,:]) + bo[n]
// ============================================================================
__global__ __launch_bounds__(256) void oproj_kernel(
    const float* __restrict__ c, const float* __restrict__ Wo,
    const float* __restrict__ bo, float* __restrict__ out)
{
    __shared__ float Xs[16][68];
    __shared__ float Ws[16][68];

    const int tid = threadIdx.x;
    const int tx = tid & 15, ty = tid >> 4;
    const int lr = tid >> 2;
    const int lc = (tid & 3) << 2;

    const int m0 = blockIdx.x * 64;
    const int n0 = blockIdx.y * 64;

    const float* xrow = c + (size_t)(m0 + lr) * DD + lc;
    const float* wrow = Wo + (size_t)(n0 + lr) * DD + lc;

    float acc[4][4] = {};

    for (int k0 = 0; k0 < DD; k0 += 16) {
        const float4 xa = *(const float4*)(xrow + k0);
        const float4 wa = *(const float4*)(wrow + k0);
        __syncthreads();
        Xs[lc + 0][lr] = xa.x; Xs[lc + 1][lr] = xa.y;
        Xs[lc + 2][lr] = xa.z; Xs[lc + 3][lr] = xa.w;
        Ws[lc + 0][lr] = wa.x; Ws[lc + 1][lr] = wa.y;
        Ws[lc + 2][lr] = wa.z; Ws[lc + 3][lr] = wa.w;
        __syncthreads();
#pragma unroll
        for (int kk = 0; kk < 16; ++kk) {
            const float4 a = *(const float4*)&Xs[kk][ty << 2];
            const float4 b = *(const float4*)&Ws[kk][tx << 2];
            const float av[4] = {a.x, a.y, a.z, a.w};
            const float bv[4] = {b.x, b.y, b.z, b.w};
#pragma unroll
            for (int i = 0; i < 4; ++i)
#pragma unroll
                for (int j = 0; j < 4; ++j)
                    acc[i][j] += av[i] * bv[j];
        }
    }

    const float4 bias = *(const float4*)&bo[n0 + (tx << 2)];
#pragma unroll
    for (int i = 0; i < 4; ++i) {
        const int m = m0 + (ty << 2) + i;
        float4 st;
        st.x = acc[i][0] + bias.x; st.y = acc[i][1] + bias.y;
        st.z = acc[i][2] + bias.z; st.w = acc[i][3] + bias.w;
        *(float4*)&out[(size_t)m * DD + n0 + (tx << 2)] = st;
    }
}

extern "C" void kernel_launch(void* const* d_in, const int* in_sizes, int n_in,
                              void* d_out, int out_size, void* d_ws, size_t ws_size,
                              hipStream_t stream) {
    const float* x  = (const float*)d_in[0];
    const float* Wq = (const float*)d_in[1];
    const float* Wk = (const float*)d_in[2];
    const float* Wv = (const float*)d_in[3];
    const float* Wo = (const float*)d_in[4];
    const float* bo = (const float*)d_in[5];
    float* out = (float*)d_out;

    const size_t per = (size_t)BB * NH * TT * HDD;   // 4,194,304 floats
    float* qws = (float*)d_ws;
    float* kws = qws + per;
    float* vws = kws + per;
    float* cws = vws + per;                          // total 64 MB scratch

    qkv_kernel<<<dim3(64, 48), 256, 0, stream>>>(x, Wq, Wk, Wv, qws, kws, vws);
    attn_kernel<<<dim3(TT / 64, BB * NH), 256, 0, stream>>>(qws, kws, vws, cws);
    oproj_kernel<<<dim3(64, 16), 256, 0, stream>>>(cws, Wo, bo, out);
}

// Round 2
// 232.097 us; speedup vs baseline: 4.7541x; 4.7541x over previous
//
#include <hip/hip_runtime.h>
#include <math.h>

#define BB 2
#define TT 2048
#define DD 1024
#define NH 16
#define HDD 64

typedef __attribute__((ext_vector_type(8))) short v8s;     // 8 bf16 in 4 VGPRs
typedef __attribute__((ext_vector_type(4))) float f32x4;   // MFMA C/D

__device__ __forceinline__ unsigned short f2bf(float f) {
    union { float f; unsigned int u; } c; c.f = f;
    unsigned int r = c.u + 0x7FFF + ((c.u >> 16) & 1);     // RNE
    return (unsigned short)(r >> 16);
}

__device__ __forceinline__ void gload_lds16(const void* g, void* l) {
    __builtin_amdgcn_global_load_lds(
        (const __attribute__((address_space(1))) void*)g,
        (__attribute__((address_space(3))) void*)l, 16, 0, 0);
}

// ============================================================================
// Cast fp32 -> bf16 for x, Wq, Wk, Wv, Wo (blockIdx.y selects tensor).
// ============================================================================
__global__ __launch_bounds__(256) void cast5_kernel(
    const float* __restrict__ x, const float* __restrict__ wq,
    const float* __restrict__ wk, const float* __restrict__ wv,
    const float* __restrict__ wo,
    unsigned short* __restrict__ xo, unsigned short* __restrict__ wqo,
    unsigned short* __restrict__ wko, unsigned short* __restrict__ wvo,
    unsigned short* __restrict__ woo)
{
    const float* s; unsigned short* d; int n4;
    switch (blockIdx.y) {
        case 0: s = x;  d = xo;  n4 = BB * TT * DD / 4; break;   // 1,048,576
        case 1: s = wq; d = wqo; n4 = DD * DD / 4; break;        //   262,144
        case 2: s = wk; d = wko; n4 = DD * DD / 4; break;
        case 3: s = wv; d = wvo; n4 = DD * DD / 4; break;
        default: s = wo; d = woo; n4 = DD * DD / 4; break;
    }
    int i = blockIdx.x * 256 + threadIdx.x;
    if (i < n4) {
        float4 v = ((const float4*)s)[i];
        ushort4 o;
        o.x = f2bf(v.x); o.y = f2bf(v.y); o.z = f2bf(v.z); o.w = f2bf(v.w);
        ((ushort4*)d)[i] = o;
    }
}

// ============================================================================
// QKV projection: bf16 MFMA B^T GEMM, 128x128 tile, BK=32, global_load_lds.
// q,k stored (B,H,T,HD) bf16; v stored TRANSPOSED (B,H,HD,T) bf16 so the
// attention PV B-fragments are contiguous LDS reads.
// ============================================================================
__global__ __launch_bounds__(256) void qkv_mfma(
    const unsigned short* __restrict__ x,
    const unsigned short* __restrict__ wq, const unsigned short* __restrict__ wk,
    const unsigned short* __restrict__ wv,
    unsigned short* __restrict__ qo, unsigned short* __restrict__ ko,
    unsigned short* __restrict__ vo)
{
    __shared__ unsigned short As[128 * 32];   // row-major [128][32], unpadded
    __shared__ unsigned short Bs[128 * 32];

    const int tid = threadIdx.x;
    const int lane = tid & 63;
    const int wid = tid >> 6;                 // wave 0..3
    const int l15 = lane & 15, quad = lane >> 4;

    const int m0 = blockIdx.x << 7;
    const int ny = blockIdx.y;                // 0..23
    const int which = ny >> 3;                // 0=q 1=k 2=v
    const int n0 = (ny & 7) << 7;
    const unsigned short* W = (which == 0) ? wq : (which == 1) ? wk : wv;

    const int wm = (wid >> 1) << 6;           // wave row offset in tile
    const int wn = (wid & 1) << 6;            // wave col offset in tile

    f32x4 acc[4][4] = {};                     // [mi][ni]

    for (int k0 = 0; k0 < DD; k0 += 32) {
        __syncthreads();
#pragma unroll
        for (int u = 0; u < 2; ++u) {
            const int f = (wid << 11) + (u << 10) + (lane << 4);  // byte off in 8KB tile
            const int row = f >> 6;                               // 64B per row (32 bf16)
            const int cs = (f & 63) >> 1;                         // ushort col
            gload_lds16(&x[(size_t)(m0 + row) * DD + k0 + cs], ((char*)As) + f);
            gload_lds16(&W[(size_t)(n0 + row) * DD + k0 + cs], ((char*)Bs) + f);
        }
        __syncthreads();

        v8s af[4], bf[4];
#pragma unroll
        for (int i = 0; i < 4; ++i)
            af[i] = *(const v8s*)(((const char*)As) + (wm + (i << 4) + l15) * 64 + (quad << 4));
#pragma unroll
        for (int j = 0; j < 4; ++j)
            bf[j] = *(const v8s*)(((const char*)Bs) + (wn + (j << 4) + l15) * 64 + (quad << 4));
#pragma unroll
        for (int i = 0; i < 4; ++i)
#pragma unroll
            for (int j = 0; j < 4; ++j)
                acc[i][j] = __builtin_amdgcn_mfma_f32_16x16x32_bf16(af[i], bf[j], acc[i][j], 0, 0, 0);
    }

    // C-layout: col = lane&15, row = quad*4 + r
    if (which < 2) {
        unsigned short* outp = (which == 0) ? qo : ko;
#pragma unroll
        for (int i = 0; i < 4; ++i)
#pragma unroll
            for (int j = 0; j < 4; ++j) {
                const int n = n0 + wn + (j << 4) + l15;
                const int h = n >> 6, hd = n & 63;
#pragma unroll
                for (int r = 0; r < 4; ++r) {
                    const int m = m0 + wm + (i << 4) + (quad << 2) + r;
                    const int b = m >> 11, t = m & 2047;
                    outp[(((size_t)(b * NH + h) * TT + t) << 6) + hd] = f2bf(acc[i][j][r]);
                }
            }
    } else {
        // v transposed: (B,H,HD,T); lane's 4 rows are consecutive t -> 8B store
#pragma unroll
        for (int i = 0; i < 4; ++i)
#pragma unroll
            for (int j = 0; j < 4; ++j) {
                const int n = n0 + wn + (j << 4) + l15;
                const int h = n >> 6, hd = n & 63;
                const int mb = m0 + wm + (i << 4) + (quad << 2);
                const int b = mb >> 11, t = mb & 2047;
                ushort4 pk;
                pk.x = f2bf(acc[i][j][0]); pk.y = f2bf(acc[i][j][1]);
                pk.z = f2bf(acc[i][j][2]); pk.w = f2bf(acc[i][j][3]);
                *(ushort4*)&vo[((((size_t)(b * NH + h) << 6) + hd) << 11) + t] = pk;
            }
    }
}

// ============================================================================
// Flash attention, bf16 MFMA.  Block = 256 thr (4 waves); each block handles
// q-tiles {x, 31-x} (uniform 33 k-tiles).  Wave w owns q-rows w*16..w*16+15.
// Qs/Ks/Vts: bf16 stride 72 (conflict-free-minimum for all frag reads).
// P: fp32 LDS stride 68, wave-private rows -> no barrier on the round-trip.
// ============================================================================
__global__ __launch_bounds__(256) void attn_mfma(
    const unsigned short* __restrict__ q, const unsigned short* __restrict__ k,
    const unsigned short* __restrict__ vt, unsigned short* __restrict__ ctx)
{
    __shared__ unsigned short Qs[64][72];
    __shared__ unsigned short Ks[64][72];
    __shared__ unsigned short Vts[64][72];
    __shared__ float Ps[64][68];

    const int tid = threadIdx.x;
    const int lane = tid & 63;
    const int wid = tid >> 6;
    const int l15 = lane & 15, quad = lane >> 4;
    const int bh = blockIdx.y;

    const unsigned short* qb = q + (size_t)bh * TT * HDD;
    const unsigned short* kb = k + (size_t)bh * TT * HDD;
    const unsigned short* vb = vt + (size_t)bh * HDD * TT;   // (HD, T)
    unsigned short* cb = ctx + (size_t)bh * TT * HDD;

    const int cr = tid >> 3;            // staging row 0..31 (x2 rounds -> 64)
    const int cc = (tid & 7) << 3;      // staging col (ushort), 16B chunks

    for (int half = 0; half < 2; ++half) {
        const int qt = half ? (31 - (int)blockIdx.x) : (int)blockIdx.x;
        const int q0 = qt << 6;

        __syncthreads();                // prev-half LDS reads done
#pragma unroll
        for (int u = 0; u < 2; ++u) {
            const int r = cr + (u << 5);
            *(uint4*)&Qs[r][cc] = *(const uint4*)&qb[(size_t)(q0 + r) * HDD + cc];
        }
        __syncthreads();

        // Q A-frags, register-resident for the whole k-loop
        v8s qf[2];
#pragma unroll
        for (int c = 0; c < 2; ++c)
            qf[c] = *(const v8s*)&Qs[(wid << 4) + l15][(c << 5) + (quad << 3)];

        float m_i[4], l_i[4];
#pragma unroll
        for (int r = 0; r < 4; ++r) { m_i[r] = -INFINITY; l_i[r] = 0.f; }
        f32x4 o[4] = {};                // [d-tile]

        for (int jt = 0; jt <= qt; ++jt) {
            const int k0 = jt << 6;
            __syncthreads();            // prev Ks/Vts reads done
#pragma unroll
            for (int u = 0; u < 2; ++u) {
                const int r = cr + (u << 5);
                *(uint4*)&Ks[r][cc] = *(const uint4*)&kb[(size_t)(k0 + r) * HDD + cc];
                *(uint4*)&Vts[r][cc] = *(const uint4*)&vb[((size_t)r << 11) + k0 + cc];
            }
            __syncthreads();

            // S = Q K^T  (wave: 16 q-rows x 64 k-cols)
            f32x4 s[4] = {};
#pragma unroll
            for (int n = 0; n < 4; ++n) {
                v8s kf0 = *(const v8s*)&Ks[(n << 4) + l15][(quad << 3)];
                v8s kf1 = *(const v8s*)&Ks[(n << 4) + l15][32 + (quad << 3)];
                s[n] = __builtin_amdgcn_mfma_f32_16x16x32_bf16(qf[0], kf0, s[n], 0, 0, 0);
                s[n] = __builtin_amdgcn_mfma_f32_16x16x32_bf16(qf[1], kf1, s[n], 0, 0, 0);
            }

            // scale + causal mask (mask-then-scale == scale-then-mask for -inf)
#pragma unroll
            for (int n = 0; n < 4; ++n) {
                const int kcol = k0 + (n << 4) + l15;
#pragma unroll
                for (int r = 0; r < 4; ++r) {
                    const int qrow = q0 + (wid << 4) + (quad << 2) + r;
                    float val = s[n][r] * 0.125f;
                    if (kcol > qrow) val = -INFINITY;
                    s[n][r] = val;
                }
            }

            // online softmax per q-row (row data lives in the 16 lanes of a quad)
            float alpha[4], rowsum[4];
#pragma unroll
            for (int r = 0; r < 4; ++r) {
                float mx = fmaxf(fmaxf(s[0][r], s[1][r]), fmaxf(s[2][r], s[3][r]));
                mx = fmaxf(mx, __shfl_xor(mx, 1));
                mx = fmaxf(mx, __shfl_xor(mx, 2));
                mx = fmaxf(mx, __shfl_xor(mx, 4));
                mx = fmaxf(mx, __shfl_xor(mx, 8));
                const float m_new = fmaxf(m_i[r], mx);
                alpha[r] = __expf(m_i[r] - m_new);
                m_i[r] = m_new;
                float sum = 0.f;
#pragma unroll
                for (int n = 0; n < 4; ++n) {
                    const float pv = __expf(s[n][r] - m_new);
                    s[n][r] = pv;
                    sum += pv;
                }
                sum += __shfl_xor(sum, 1);
                sum += __shfl_xor(sum, 2);
                sum += __shfl_xor(sum, 4);
                sum += __shfl_xor(sum, 8);
                rowsum[r] = sum;
                l_i[r] = l_i[r] * alpha[r] + sum;
            }
#pragma unroll
            for (int n = 0; n < 4; ++n)
#pragma unroll
                for (int r = 0; r < 4; ++r)
                    o[n][r] *= alpha[r];

            // P: C-layout regs -> LDS (wave-private rows, no barrier needed)
#pragma unroll
            for (int n = 0; n < 4; ++n)
#pragma unroll
                for (int r = 0; r < 4; ++r)
                    Ps[(wid << 4) + (quad << 2) + r][(n << 4) + l15] = s[n][r];

            // P A-frags (fp32 LDS -> bf16)
            v8s pf[2];
#pragma unroll
            for (int c = 0; c < 2; ++c) {
                const float4 p0 = *(const float4*)&Ps[(wid << 4) + l15][(c << 5) + (quad << 3)];
                const float4 p1 = *(const float4*)&Ps[(wid << 4) + l15][(c << 5) + (quad << 3) + 4];
                v8s t;
                t[0] = (short)f2bf(p0.x); t[1] = (short)f2bf(p0.y);
                t[2] = (short)f2bf(p0.z); t[3] = (short)f2bf(p0.w);
                t[4] = (short)f2bf(p1.x); t[5] = (short)f2bf(p1.y);
                t[6] = (short)f2bf(p1.z); t[7] = (short)f2bf(p1.w);
                pf[c] = t;
            }

            // O += P V   (B-frag from Vts: B[k][n=d] = Vt[d][k], contiguous)
#pragma unroll
            for (int n = 0; n < 4; ++n) {
                v8s vf0 = *(const v8s*)&Vts[(n << 4) + l15][(quad << 3)];
                v8s vf1 = *(const v8s*)&Vts[(n << 4) + l15][32 + (quad << 3)];
                o[n] = __builtin_amdgcn_mfma_f32_16x16x32_bf16(pf[0], vf0, o[n], 0, 0, 0);
                o[n] = __builtin_amdgcn_mfma_f32_16x16x32_bf16(pf[1], vf1, o[n], 0, 0, 0);
            }
        }

        // normalize + store ctx bf16 (B,H,T,HD)
#pragma unroll
        for (int r = 0; r < 4; ++r) {
            const float linv = 1.f / l_i[r];
            const int t = q0 + (wid << 4) + (quad << 2) + r;
#pragma unroll
            for (int n = 0; n < 4; ++n)
                cb[((size_t)t << 6) + (n << 4) + l15] = f2bf(o[n][r] * linv);
        }
    }
}

// ============================================================================
// Output projection: ctx (bf16, flat 4096x1024 = faithful reshape) x Wo^T + bo
// Same MFMA GEMM core; fp32 output.
// ============================================================================
__global__ __launch_bounds__(256) void oproj_mfma(
    const unsigned short* __restrict__ c, const unsigned short* __restrict__ wo,
    const float* __restrict__ bo, float* __restrict__ out)
{
    __shared__ unsigned short As[128 * 32];
    __shared__ unsigned short Bs[128 * 32];

    const int tid = threadIdx.x;
    const int lane = tid & 63;
    const int wid = tid >> 6;
    const int l15 = lane & 15, quad = lane >> 4;

    const int m0 = blockIdx.x << 7;
    const int n0 = blockIdx.y << 7;
    const int wm = (wid >> 1) << 6, wn = (wid & 1) << 6;

    f32x4 acc[4][4] = {};

    for (int k0 = 0; k0 < DD; k0 += 32) {
        __syncthreads();
#pragma unroll
        for (int u = 0; u < 2; ++u) {
            const int f = (wid << 11) + (u << 10) + (lane << 4);
            const int row = f >> 6;
            const int cs = (f & 63) >> 1;
            gload_lds16(&c[(size_t)(m0 + row) * DD + k0 + cs], ((char*)As) + f);
            gload_lds16(&wo[(size_t)(n0 + row) * DD + k0 + cs], ((char*)Bs) + f);
        }
        __syncthreads();

        v8s af[4], bf[4];
#pragma unroll
        for (int i = 0; i < 4; ++i)
            af[i] = *(const v8s*)(((const char*)As) + (wm + (i << 4) + l15) * 64 + (quad << 4));
#pragma unroll
        for (int j = 0; j < 4; ++j)
            bf[j] = *(const v8s*)(((const char*)Bs) + (wn + (j << 4) + l15) * 64 + (quad << 4));
#pragma unroll
        for (int i = 0; i < 4; ++i)
#pragma unroll
            for (int j = 0; j < 4; ++j)
                acc[i][j] = __builtin_amdgcn_mfma_f32_16x16x32_bf16(af[i], bf[j], acc[i][j], 0, 0, 0);
    }

#pragma unroll
    for (int j = 0; j < 4; ++j) {
        const int n = n0 + wn + (j << 4) + l15;
        const float bias = bo[n];
#pragma unroll
        for (int i = 0; i < 4; ++i) {
            const int mb = m0 + wm + (i << 4) + (quad << 2);
#pragma unroll
            for (int r = 0; r < 4; ++r)
                out[(size_t)(mb + r) * DD + n] = acc[i][j][r] + bias;
        }
    }
}

extern "C" void kernel_launch(void* const* d_in, const int* in_sizes, int n_in,
                              void* d_out, int out_size, void* d_ws, size_t ws_size,
                              hipStream_t stream) {
    const float* x  = (const float*)d_in[0];
    const float* Wq = (const float*)d_in[1];
    const float* Wk = (const float*)d_in[2];
    const float* Wv = (const float*)d_in[3];
    const float* Wo = (const float*)d_in[4];
    const float* bo = (const float*)d_in[5];
    float* out = (float*)d_out;

    const size_t NX = (size_t)BB * TT * DD;      // 4,194,304
    const size_t NW = (size_t)DD * DD;           // 1,048,576

    unsigned short* xb  = (unsigned short*)d_ws;
    unsigned short* wqb = xb + NX;
    unsigned short* wkb = wqb + NW;
    unsigned short* wvb = wkb + NW;
    unsigned short* wob = wvb + NW;
    unsigned short* qb  = wob + NW;
    unsigned short* kb  = qb + NX;
    unsigned short* vtb = kb + NX;
    unsigned short* cbuf = vtb + NX;             // total ~50.3 MB

    cast5_kernel<<<dim3(4096, 5), 256, 0, stream>>>(x, Wq, Wk, Wv, Wo,
                                                    xb, wqb, wkb, wvb, wob);
    qkv_mfma<<<dim3(32, 24), 256, 0, stream>>>(xb, wqb, wkb, wvb, qb, kb, vtb);
    attn_mfma<<<dim3(16, 32), 256, 0, stream>>>(qb, kb, vtb, cbuf);
    oproj_mfma<<<dim3(32, 8), 256, 0, stream>>>(cbuf, wob, bo, out);
}